// Round 17
// baseline (238.374 us; speedup 1.0000x reference)
//
#include <hip/hip_runtime.h>
#include <hip/hip_fp16.h>

// Problem constants
#define BB 2
#define CC 64
#define KK 27
#define S_TOT 32768  // 32^3
#define BN_EPS 1e-5f
#define KL_STRIDE 66  // pad: (27g+k)*33 mod 32 distinct for g=0..7 -> no bank conflict

// ws layout: xT[2][32768][64] floats (16.8 MB).
#define XT_FLOATS ((size_t)BB * S_TOT * CC)

// ---------------------------------------------------------------------------
// K1: transpose x[b][c][s] -> xT[b][s][c]  (LDS-tiled, proven since R5).
// ---------------------------------------------------------------------------
__global__ __launch_bounds__(256) void xpose_kernel(const float* __restrict__ x,
                                                    float* __restrict__ xT) {
  __shared__ float t[64 * 65];
  const int tid = threadIdx.x;
  const int blk = blockIdx.x;
  const int b   = blk >> 9;
  const int s0  = (blk & 511) << 6;
  const float* xb = x + ((size_t)b << 21);
  {
    const int cq = tid >> 4;
    const int sq = (tid & 15) << 2;
#pragma unroll
    for (int i = 0; i < 4; ++i) {
      int c = cq + (i << 4);
      float4 v = *(const float4*)(xb + ((size_t)c << 15) + s0 + sq);
      t[c * 65 + sq + 0] = v.x;
      t[c * 65 + sq + 1] = v.y;
      t[c * 65 + sq + 2] = v.z;
      t[c * 65 + sq + 3] = v.w;
    }
  }
  __syncthreads();
  {
    float* xTb = xT + ((size_t)b << 21);
    const int si = tid >> 2;
    const int cb = (tid & 3) << 4;
#pragma unroll
    for (int j = 0; j < 4; ++j) {
      int c = cb + (j << 2);
      float4 w;
      w.x = t[(c + 0) * 65 + si];
      w.y = t[(c + 1) * 65 + si];
      w.z = t[(c + 2) * 65 + si];
      w.w = t[(c + 3) * 65 + si];
      *(float4*)(xTb + ((size_t)(s0 + si) << 6) + c) = w;
    }
  }
}

// ---------------------------------------------------------------------------
// K2: FUSED kergen + gather, p-MERGED (block = (b, tile), 4 waves, all 8
// groups). The R16 diagnosis: gather was L2-BW-bound (8x over-read from
// 8/64-channel slicing + p-split row re-reads; occupancy changes neutral).
// Fix: phase 3 remaps LANE = CHANNEL — per (s,k) the wave reads xT row o2
// as one fully-used 256B coalesced transaction. Gather L2 read: ~1.8GB ->
// 452MB.
//   Phase 0: offs u16 table -> LDS
//   Phase 1: GEMM1+BN+ReLU -> sv fp16 (wave w: channels 16w..16w+15; no
//            p-duplication anymore)
//   Phase 2: GEMM2 -> kl fp16 LDS, wave w owns groups 2w,2w+1; 6 runtime
//            chunks of the R10-proven acc[9] shape; LDS stores (32-bit addr,
//            no store-address-cluster spill risk)
//   barrier (kl now cross-wave consumed)
//   Phase 3: lane c = tid&63, wave w covers columns w*16..w*16+15, 4 at a
//            time with SCALAR accs (spill-proof); offs/row index wave-uniform
//            -> readfirstlane -> SGPR-base loads; float4 out stores.
// LDS: sv 8KB + kl 216*66*2=27.8KB + offs 3.4KB = 40.2KB -> 4 blocks/CU.
// Grid 1024 = exactly 4/CU.
// ---------------------------------------------------------------------------
__global__ __launch_bounds__(256, 4) void invol_fused_xt(
    const float* __restrict__ xT, const float* __restrict__ wr,
    const float* __restrict__ wsp, const float* __restrict__ gamma,
    const float* __restrict__ beta, const float* __restrict__ mean,
    const float* __restrict__ var, float* __restrict__ out) {
  __shared__ __half sv[CC * 64];               // 8 KB
  __shared__ __half kl[8 * KK * KL_STRIDE];    // 27.84 KB
  __shared__ unsigned short offs[KK * 64];     // 3.375 KB

  const int tid = threadIdx.x;
  const int blk = blockIdx.x;
  const int b   = blk >> 9;
  const int s0  = (blk & 511) << 6;
  const int si  = tid & 63;
  const int w   = __builtin_amdgcn_readfirstlane(tid >> 6);  // wave 0..3

  // ---- Phase 0: offset table ----
  // f = k*32768 + s, mixed radix [od:32][oh:32][ow:32][kd:3][kh:3][kw:3];
  // (dd,hh,ww) = (od+kd-1, oh+kh-1, ow+kw-1); 0xFFFF if OOB (zero pad).
  for (int i = tid; i < KK * 64; i += 256) {
    int k  = i >> 6;
    int f  = (k << 15) + s0 + (i & 63);
    int kw = f % 3; int u = f / 3;
    int kh = u % 3; u /= 3;
    int kd = u % 3; u /= 3;
    int ww = (u & 31) + kw - 1; u >>= 5;
    int hh = (u & 31) + kh - 1; u >>= 5;
    int dd = u + kd - 1;
    unsigned short off = 0xFFFFu;
    if (((unsigned)ww < 32u) & ((unsigned)hh < 32u) & ((unsigned)dd < 32u))
      off = (unsigned short)((dd << 10) + (hh << 5) + ww);
    offs[i] = off;
  }

  // ---- Phase 1: GEMM1 + BN + ReLU -> sv fp16 (16 channels per wave) ----
  {
    const float* xrow = xT + ((((size_t)b << 15) + s0 + si) << 6);  // xT[b][s][*]
    float acc[16];
#pragma unroll
    for (int j = 0; j < 16; ++j) acc[j] = 0.f;
#pragma unroll
    for (int half = 0; half < 2; ++half) {
      float xv[32];
#pragma unroll
      for (int q = 0; q < 8; ++q) {
        float4 v = *(const float4*)(xrow + half * 32 + q * 4);
        xv[q * 4 + 0] = v.x;
        xv[q * 4 + 1] = v.y;
        xv[q * 4 + 2] = v.z;
        xv[q * 4 + 3] = v.w;
      }
      const float* wrw = wr + (w * 16) * CC + half * 32;
#pragma unroll
      for (int j = 0; j < 16; ++j) {
        const float* r0 = wrw + j * CC;
        float a0 = 0.f, a1 = 0.f;
#pragma unroll
        for (int c = 0; c < 32; c += 2) {
          a0 = fmaf(r0[c],     xv[c],     a0);
          a1 = fmaf(r0[c + 1], xv[c + 1], a1);
        }
        acc[j] += a0 + a1;
      }
    }
#pragma unroll
    for (int j = 0; j < 16; ++j) {
      int o = w * 16 + j;
      float v = (acc[j] - mean[o]) * rsqrtf(var[o] + BN_EPS) * gamma[o] + beta[o];
      sv[o * 64 + si] = __float2half(v > 0.f ? v : 0.f);
    }
  }
  __syncthreads();  // covers sv + offs

  // ---- Phase 2: GEMM2 -> kl fp16 LDS. Wave w owns groups 2w, 2w+1. ----
#pragma unroll 1
  for (int h = 0; h < 2; ++h) {
    const int g2 = (w << 1) + h;
#pragma unroll 1
    for (int jt = 0; jt < 3; ++jt) {
      float acc[9];
#pragma unroll
      for (int j = 0; j < 9; ++j) acc[j] = 0.f;
      const float* wsb = wsp + (g2 * KK + jt * 9) * CC;
#pragma unroll
      for (int e = 0; e < 8; ++e) {
        float xv[8];
#pragma unroll
        for (int c = 0; c < 8; ++c)
          xv[c] = __half2float(sv[(e * 8 + c) * 64 + si]);
        const float* wsw = wsb + e * 8;
#pragma unroll
        for (int j = 0; j < 9; ++j) {
          const float* r = wsw + j * CC;
          float a0 = 0.f, a1 = 0.f;
#pragma unroll
          for (int c = 0; c < 8; c += 2) {
            a0 = fmaf(r[c],     xv[c],     a0);
            a1 = fmaf(r[c + 1], xv[c + 1], a1);
          }
          acc[j] += a0 + a1;
        }
      }
      __half* klt = kl + (size_t)(g2 * KK + jt * 9) * KL_STRIDE + si;
#pragma unroll
      for (int j = 0; j < 9; ++j)
        klt[j * KL_STRIDE] = __float2half(acc[j]);
    }
  }
  __syncthreads();  // kl consumed cross-wave in phase 3

  // ---- Phase 3: gather-reduce, LANE = CHANNEL ----
  // Wave w covers tile columns sl = w*16 .. w*16+15, 4 at a time.
  // Per (sl,k): row index o2 is wave-uniform (readfirstlane -> SGPR base);
  // the wave reads xTb[o2*64 + lane] = one coalesced fully-used 256B line.
  {
    const int c   = si;        // lane = channel
    const int gl  = c >> 3;    // its group
    const float* xTb = xT + ((size_t)b << 21) + c;
    const __half* klg = kl + (size_t)(gl * KK) * KL_STRIDE;
    const int sl0 = w << 4;

#pragma unroll 1
    for (int t = 0; t < 16; t += 4) {
      const int sl = sl0 + t;
      float a0 = 0.f, a1 = 0.f, a2 = 0.f, a3 = 0.f;
#pragma unroll 2
      for (int k = 0; k < KK; ++k) {
        const int obase = (k << 6) + sl;
        unsigned of0 = __builtin_amdgcn_readfirstlane(offs[obase + 0]);
        unsigned of1 = __builtin_amdgcn_readfirstlane(offs[obase + 1]);
        unsigned of2 = __builtin_amdgcn_readfirstlane(offs[obase + 2]);
        unsigned of3 = __builtin_amdgcn_readfirstlane(offs[obase + 3]);
        const __half* klk = klg + (size_t)k * KL_STRIDE + sl;
        float kv0 = (of0 != 0xFFFFu) ? __half2float(klk[0]) : 0.f;
        float kv1 = (of1 != 0xFFFFu) ? __half2float(klk[1]) : 0.f;
        float kv2 = (of2 != 0xFFFFu) ? __half2float(klk[2]) : 0.f;
        float kv3 = (of3 != 0xFFFFu) ? __half2float(klk[3]) : 0.f;
        unsigned o0 = (of0 != 0xFFFFu) ? of0 : 0u;
        unsigned o1 = (of1 != 0xFFFFu) ? of1 : 0u;
        unsigned o2 = (of2 != 0xFFFFu) ? of2 : 0u;
        unsigned o3 = (of3 != 0xFFFFu) ? of3 : 0u;
        float x0 = xTb[(size_t)o0 << 6];
        float x1 = xTb[(size_t)o1 << 6];
        float x2 = xTb[(size_t)o2 << 6];
        float x3 = xTb[(size_t)o3 << 6];
        a0 = fmaf(kv0, x0, a0);
        a1 = fmaf(kv1, x1, a1);
        a2 = fmaf(kv2, x2, a2);
        a3 = fmaf(kv3, x3, a3);
      }
      float4 v;
      v.x = a0; v.y = a1; v.z = a2; v.w = a3;
      *(float4*)(out + (((size_t)b * CC + c) << 15) + s0 + sl) = v;
    }
  }
}

// ---------------------------------------------------------------------------
// Fallback (ws too small): exact R4 fused kernel — known-good 144 us.
// ---------------------------------------------------------------------------
__global__ __launch_bounds__(256, 8) void invol_fused(
    const float* __restrict__ x, const float* __restrict__ wr,
    const float* __restrict__ wsp, const float* __restrict__ gamma,
    const float* __restrict__ beta, const float* __restrict__ mean,
    const float* __restrict__ var, float* __restrict__ out) {
  __shared__ float sv[CC * 64];
  __shared__ int offs[KK * 64];

  const int tid = threadIdx.x;
  const int blk = blockIdx.x;
  const int b   = blk >> 10;
  const int p   = (blk >> 9) & 1;
  const int s0  = (blk & 511) << 6;
  const int si  = tid & 63;
  const int w   = __builtin_amdgcn_readfirstlane(tid >> 6);
  const int g   = (p << 2) + w;

  const float* xb  = x + ((size_t)b << 21);
  const float* xs0 = xb + s0 + si;

  for (int i = tid; i < KK * 64; i += 256) {
    int k  = i >> 6;
    int f  = (k << 15) + s0 + (i & 63);
    int kw = f % 3; int u = f / 3;
    int kh = u % 3; u /= 3;
    int kd = u % 3; u /= 3;
    int ww = (u & 31) + kw - 1; u >>= 5;
    int hh = (u & 31) + kh - 1; u >>= 5;
    int dd = u + kd - 1;
    int off = -1;
    if (((unsigned)ww < 32u) & ((unsigned)hh < 32u) & ((unsigned)dd < 32u))
      off = (dd << 10) + (hh << 5) + ww;
    offs[i] = off;
  }

  {
    float acc[16];
#pragma unroll
    for (int j = 0; j < 16; ++j) acc[j] = 0.f;
#pragma unroll
    for (int half = 0; half < 2; ++half) {
      float xv[32];
#pragma unroll
      for (int c = 0; c < 32; ++c)
        xv[c] = xs0[(size_t)(half * 32 + c) << 15];
      const float* wrw = wr + (w * 16) * CC + half * 32;
#pragma unroll
      for (int j = 0; j < 16; ++j) {
        const float* r0 = wrw + j * CC;
        float a0 = 0.f, a1 = 0.f;
#pragma unroll
        for (int c = 0; c < 32; c += 2) {
          a0 = fmaf(r0[c],     xv[c],     a0);
          a1 = fmaf(r0[c + 1], xv[c + 1], a1);
        }
        acc[j] += a0 + a1;
      }
    }
#pragma unroll
    for (int j = 0; j < 16; ++j) {
      int o = w * 16 + j;
      float v = (acc[j] - mean[o]) * rsqrtf(var[o] + BN_EPS) * gamma[o] + beta[o];
      sv[o * 64 + si] = v > 0.f ? v : 0.f;
    }
  }
  __syncthreads();

  float kreg[27];
#pragma unroll
  for (int j = 0; j < KK; ++j) kreg[j] = 0.f;
#pragma unroll
  for (int e = 0; e < 8; ++e) {
    float xv[8];
#pragma unroll
    for (int c = 0; c < 8; ++c) xv[c] = sv[(e * 8 + c) * 64 + si];
    const float* wsw = wsp + (g * KK) * CC + e * 8;
#pragma unroll
    for (int j = 0; j < KK; ++j) {
      const float* r = wsw + j * CC;
      float a0 = 0.f, a1 = 0.f;
#pragma unroll
      for (int c = 0; c < 8; c += 2) {
        a0 = fmaf(r[c],     xv[c],     a0);
        a1 = fmaf(r[c + 1], xv[c + 1], a1);
      }
      kreg[j] += a0 + a1;
    }
  }

  {
    const int c0 = g << 3;
    const float* xc0 = xb + ((size_t)c0 << 15);
    float oacc[8];
#pragma unroll
    for (int i = 0; i < 8; ++i) oacc[i] = 0.f;
#pragma unroll
    for (int k = 0; k < KK; ++k) {
      int off = offs[(k << 6) + si];
      float kv = kreg[k];
      if (off >= 0) {
#pragma unroll
        for (int c8 = 0; c8 < 8; ++c8)
          oacc[c8] = fmaf(kv, xc0[off + (c8 << 15)], oacc[c8]);
      }
    }
    float* ob = out + (((size_t)b * CC + c0) << 15) + s0 + si;
#pragma unroll
    for (int i = 0; i < 8; ++i) ob[(size_t)i << 15] = oacc[i];
  }
}

extern "C" void kernel_launch(void* const* d_in, const int* in_sizes, int n_in,
                              void* d_out, int out_size, void* d_ws, size_t ws_size,
                              hipStream_t stream) {
  const float* x     = (const float*)d_in[0];
  const float* wr    = (const float*)d_in[1];
  const float* wsp   = (const float*)d_in[2];
  const float* gamma = (const float*)d_in[3];
  const float* beta  = (const float*)d_in[4];
  const float* mean  = (const float*)d_in[5];
  const float* var   = (const float*)d_in[6];
  float* out = (float*)d_out;

  const size_t need = XT_FLOATS * sizeof(float);  // 16.8 MB
  if (ws_size >= need) {
    float* xT = (float*)d_ws;
    xpose_kernel<<<BB * (S_TOT / 64), 256, 0, stream>>>(x, xT);
    invol_fused_xt<<<BB * (S_TOT / 64), 256, 0, stream>>>(
        xT, wr, wsp, gamma, beta, mean, var, out);
  } else {
    invol_fused<<<BB * 2 * (S_TOT / 64), 256, 0, stream>>>(
        x, wr, wsp, gamma, beta, mean, var, out);
  }
}

// Round 18
// 111.562 us; speedup vs baseline: 2.1367x; 2.1367x over previous
//
#include <hip/hip_runtime.h>
#include <hip/hip_fp16.h>

// Problem constants
#define BB 2
#define CC 64
#define KK 27
#define S_TOT 32768  // 32^3
#define BN_EPS 1e-5f
#define SV_STRIDE 66  // pad: B-frag group reads land on disjoint bank octets
#define KL_STRIDE 66

typedef _Float16 h8 __attribute__((ext_vector_type(8)));
typedef float f4v __attribute__((ext_vector_type(4)));

// ws layout: xT[2][32768][64] floats (16.8 MB).
#define XT_FLOATS ((size_t)BB * S_TOT * CC)

// ---------------------------------------------------------------------------
// K1: transpose x[b][c][s] -> xT[b][s][c]  (LDS-tiled, proven since R5).
// ---------------------------------------------------------------------------
__global__ __launch_bounds__(256) void xpose_kernel(const float* __restrict__ x,
                                                    float* __restrict__ xT) {
  __shared__ float t[64 * 65];
  const int tid = threadIdx.x;
  const int blk = blockIdx.x;
  const int b   = blk >> 9;
  const int s0  = (blk & 511) << 6;
  const float* xb = x + ((size_t)b << 21);
  {
    const int cq = tid >> 4;
    const int sq = (tid & 15) << 2;
#pragma unroll
    for (int i = 0; i < 4; ++i) {
      int c = cq + (i << 4);
      float4 v = *(const float4*)(xb + ((size_t)c << 15) + s0 + sq);
      t[c * 65 + sq + 0] = v.x;
      t[c * 65 + sq + 1] = v.y;
      t[c * 65 + sq + 2] = v.z;
      t[c * 65 + sq + 3] = v.w;
    }
  }
  __syncthreads();
  {
    float* xTb = xT + ((size_t)b << 21);
    const int si = tid >> 2;
    const int cb = (tid & 3) << 4;
#pragma unroll
    for (int j = 0; j < 4; ++j) {
      int c = cb + (j << 2);
      float4 w;
      w.x = t[(c + 0) * 65 + si];
      w.y = t[(c + 1) * 65 + si];
      w.z = t[(c + 2) * 65 + si];
      w.w = t[(c + 3) * 65 + si];
      *(float4*)(xTb + ((size_t)(s0 + si) << 6) + c) = w;
    }
  }
}

// ---------------------------------------------------------------------------
// K2: FUSED — R16 base (champion: p-split 2048x256, phase 0/1 and gather
// byte-identical except LDS strides), with ONE structural change:
//   Phase 2 (GEMM2, 906M MACs, the dominant VALU phase) moved to MFMA
//   (v_mfma_f32_16x16x32_f16): A = w_span 16x32 fp16 (cast on load),
//   B = sv 32x16 (already fp16 in LDS), fp32 accum, 2 chained MFMAs = K64.
//   Wave w owns col-tile w (cols 16w..16w+15); loops row-tiles covering
//   kernel-rows 108p..108p+107 (edge tiles masked on kl write; A-row
//   clamped at 215). C layout (m89-verified): col=lane&15,
//   row=(lane>>4)*4+reg. A: lane&15=row, k=8*(lane>>4)+e. B: mirrored.
// kl rows local (27w+k) — exactly what the R16 gather already indexes.
// LDS: sv 64*66*2=8.25K + kl 108*66*2=13.9K + offs 3.4K = 25.6KB -> 6/CU.
// Extra barrier after phase 2 (kl now produced cross-wave).
// ---------------------------------------------------------------------------
__global__ __launch_bounds__(256, 4) void invol_fused_xt(
    const float* __restrict__ xT, const float* __restrict__ wr,
    const float* __restrict__ wsp, const float* __restrict__ gamma,
    const float* __restrict__ beta, const float* __restrict__ mean,
    const float* __restrict__ var, float* __restrict__ out) {
  __shared__ __half sv[CC * SV_STRIDE];        // 8.25 KB
  __shared__ __half kl[108 * KL_STRIDE];       // 13.9 KB (this block's 4 groups)
  __shared__ unsigned short offs[KK * 64];     // 3.375 KB

  const int tid = threadIdx.x;
  const int blk = blockIdx.x;
  const int b   = blk >> 10;
  const int p   = (blk >> 9) & 1;
  const int s0  = (blk & 511) << 6;
  const int si  = tid & 63;
  const int w   = __builtin_amdgcn_readfirstlane(tid >> 6);  // wave 0..3
  const int g   = (p << 2) + w;                               // group 0..7
  const int c0  = g << 3;

  // ---- Phase 0: offset table ----
  // f = k*32768 + s, mixed radix [od:32][oh:32][ow:32][kd:3][kh:3][kw:3];
  // (dd,hh,ww) = (od+kd-1, oh+kh-1, ow+kw-1); 0xFFFF if OOB (zero pad).
  for (int i = tid; i < KK * 64; i += 256) {
    int k  = i >> 6;
    int f  = (k << 15) + s0 + (i & 63);
    int kw = f % 3; int u = f / 3;
    int kh = u % 3; u /= 3;
    int kd = u % 3; u /= 3;
    int ww = (u & 31) + kw - 1; u >>= 5;
    int hh = (u & 31) + kh - 1; u >>= 5;
    int dd = u + kd - 1;
    unsigned short off = 0xFFFFu;
    if (((unsigned)ww < 32u) & ((unsigned)hh < 32u) & ((unsigned)dd < 32u))
      off = (unsigned short)((dd << 10) + (hh << 5) + ww);
    offs[i] = off;
  }

  // ---- Phase 1: GEMM1 + BN + ReLU -> sv fp16 (R16-proven, stride 66) ----
  {
    const float* xrow = xT + ((((size_t)b << 15) + s0 + si) << 6);  // xT[b][s][*]
    float acc[16];
#pragma unroll
    for (int j = 0; j < 16; ++j) acc[j] = 0.f;
#pragma unroll
    for (int half = 0; half < 2; ++half) {
      float xv[32];
#pragma unroll
      for (int q = 0; q < 8; ++q) {
        float4 v = *(const float4*)(xrow + half * 32 + q * 4);
        xv[q * 4 + 0] = v.x;
        xv[q * 4 + 1] = v.y;
        xv[q * 4 + 2] = v.z;
        xv[q * 4 + 3] = v.w;
      }
      const float* wrw = wr + (w * 16) * CC + half * 32;
#pragma unroll
      for (int j = 0; j < 16; ++j) {
        const float* r0 = wrw + j * CC;
        float a0 = 0.f, a1 = 0.f;
#pragma unroll
        for (int c = 0; c < 32; c += 2) {
          a0 = fmaf(r0[c],     xv[c],     a0);
          a1 = fmaf(r0[c + 1], xv[c + 1], a1);
        }
        acc[j] += a0 + a1;
      }
    }
#pragma unroll
    for (int j = 0; j < 16; ++j) {
      int o = w * 16 + j;
      float v = (acc[j] - mean[o]) * rsqrtf(var[o] + BN_EPS) * gamma[o] + beta[o];
      sv[o * SV_STRIDE + si] = __float2half(v > 0.f ? v : 0.f);
    }
  }
  __syncthreads();  // sv + offs ready

  // ---- Phase 2: GEMM2 via MFMA -> kl fp16 ----
  {
    const int lane = tid & 63;
    const int lo   = lane & 15;       // row (A) / col (B,C) within tile
    const int hi   = lane >> 4;       // k-group
    const int kb   = hi << 3;         // k base within 32-chunk
    const int col  = (w << 4) + lo;   // this wave's col-tile = w
    const _Float16* svh = (const _Float16*)sv;
    _Float16* klh = (_Float16*)kl;

    // B fragments (shared across all row-tiles): B[k][col] from sv
    h8 b0, b1;
#pragma unroll
    for (int e = 0; e < 8; ++e) {
      b0[e] = svh[(kb + e) * SV_STRIDE + col];
      b1[e] = svh[(32 + kb + e) * SV_STRIDE + col];
    }

    const int rt0 = 6 * p;            // p=0: tiles 0..6 ; p=1: tiles 6..13
    const int rt1 = 7 + 7 * p;
    const int lbase = 108 * p;
#pragma unroll 1
    for (int rt = rt0; rt < rt1; ++rt) {
      int row  = (rt << 4) + lo;
      int rowc = row > 215 ? 215 : row;         // clamp A OOB (masked below)
      const float* ar = wsp + rowc * CC;
      float4 va0 = *(const float4*)(ar + kb);
      float4 va1 = *(const float4*)(ar + kb + 4);
      float4 vb0 = *(const float4*)(ar + 32 + kb);
      float4 vb1 = *(const float4*)(ar + 32 + kb + 4);
      h8 a0, a1;
      a0[0] = (_Float16)va0.x; a0[1] = (_Float16)va0.y;
      a0[2] = (_Float16)va0.z; a0[3] = (_Float16)va0.w;
      a0[4] = (_Float16)va1.x; a0[5] = (_Float16)va1.y;
      a0[6] = (_Float16)va1.z; a0[7] = (_Float16)va1.w;
      a1[0] = (_Float16)vb0.x; a1[1] = (_Float16)vb0.y;
      a1[2] = (_Float16)vb0.z; a1[3] = (_Float16)vb0.w;
      a1[4] = (_Float16)vb1.x; a1[5] = (_Float16)vb1.y;
      a1[6] = (_Float16)vb1.z; a1[7] = (_Float16)vb1.w;
      f4v acc = {0.f, 0.f, 0.f, 0.f};
      acc = __builtin_amdgcn_mfma_f32_16x16x32_f16(a0, b0, acc, 0, 0, 0);
      acc = __builtin_amdgcn_mfma_f32_16x16x32_f16(a1, b1, acc, 0, 0, 0);
#pragma unroll
      for (int r = 0; r < 4; ++r) {
        int kr = (rt << 4) + (hi << 2) + r;     // global kernel-row
        int lr = kr - lbase;                    // local row 27w'+k
        if ((unsigned)lr < 108u)
          klh[lr * KL_STRIDE + col] = (_Float16)acc[r];
      }
    }
  }
  __syncthreads();  // kl produced cross-wave

  // ---- Phase 3: gather-reduce from xT (R16-proven, stride 66) ----
  {
    const float* xTb = xT + ((size_t)b << 21) + c0;
    const __half* klr = kl + (w * KK) * KL_STRIDE + si;
    float oacc[8];
#pragma unroll
    for (int i = 0; i < 8; ++i) oacc[i] = 0.f;

#pragma unroll 2
    for (int k = 0; k < KK; ++k) {
      unsigned off = offs[(k << 6) + si];
      float kvr = __half2float(klr[k * KL_STRIDE]);
      float kv  = (off != 0xFFFFu) ? kvr : 0.f;
      unsigned o2 = (off != 0xFFFFu) ? off : 0u;
      const float* xp = xTb + ((size_t)o2 << 6);
      float4 v0 = *(const float4*)xp;
      float4 v1 = *(const float4*)(xp + 4);
      oacc[0] = fmaf(kv, v0.x, oacc[0]);
      oacc[1] = fmaf(kv, v0.y, oacc[1]);
      oacc[2] = fmaf(kv, v0.z, oacc[2]);
      oacc[3] = fmaf(kv, v0.w, oacc[3]);
      oacc[4] = fmaf(kv, v1.x, oacc[4]);
      oacc[5] = fmaf(kv, v1.y, oacc[5]);
      oacc[6] = fmaf(kv, v1.z, oacc[6]);
      oacc[7] = fmaf(kv, v1.w, oacc[7]);
    }

    float* ob = out + (((size_t)b * CC + c0) << 15) + s0 + si;
#pragma unroll
    for (int i = 0; i < 8; ++i) ob[(size_t)i << 15] = oacc[i];
  }
}

// ---------------------------------------------------------------------------
// Fallback (ws too small): exact R4 fused kernel — known-good 144 us.
// ---------------------------------------------------------------------------
__global__ __launch_bounds__(256, 8) void invol_fused(
    const float* __restrict__ x, const float* __restrict__ wr,
    const float* __restrict__ wsp, const float* __restrict__ gamma,
    const float* __restrict__ beta, const float* __restrict__ mean,
    const float* __restrict__ var, float* __restrict__ out) {
  __shared__ float sv[CC * 64];
  __shared__ int offs[KK * 64];

  const int tid = threadIdx.x;
  const int blk = blockIdx.x;
  const int b   = blk >> 10;
  const int p   = (blk >> 9) & 1;
  const int s0  = (blk & 511) << 6;
  const int si  = tid & 63;
  const int w   = __builtin_amdgcn_readfirstlane(tid >> 6);
  const int g   = (p << 2) + w;

  const float* xb  = x + ((size_t)b << 21);
  const float* xs0 = xb + s0 + si;

  for (int i = tid; i < KK * 64; i += 256) {
    int k  = i >> 6;
    int f  = (k << 15) + s0 + (i & 63);
    int kw = f % 3; int u = f / 3;
    int kh = u % 3; u /= 3;
    int kd = u % 3; u /= 3;
    int ww = (u & 31) + kw - 1; u >>= 5;
    int hh = (u & 31) + kh - 1; u >>= 5;
    int dd = u + kd - 1;
    int off = -1;
    if (((unsigned)ww < 32u) & ((unsigned)hh < 32u) & ((unsigned)dd < 32u))
      off = (dd << 10) + (hh << 5) + ww;
    offs[i] = off;
  }

  {
    float acc[16];
#pragma unroll
    for (int j = 0; j < 16; ++j) acc[j] = 0.f;
#pragma unroll
    for (int half = 0; half < 2; ++half) {
      float xv[32];
#pragma unroll
      for (int c = 0; c < 32; ++c)
        xv[c] = xs0[(size_t)(half * 32 + c) << 15];
      const float* wrw = wr + (w * 16) * CC + half * 32;
#pragma unroll
      for (int j = 0; j < 16; ++j) {
        const float* r0 = wrw + j * CC;
        float a0 = 0.f, a1 = 0.f;
#pragma unroll
        for (int c = 0; c < 32; c += 2) {
          a0 = fmaf(r0[c],     xv[c],     a0);
          a1 = fmaf(r0[c + 1], xv[c + 1], a1);
        }
        acc[j] += a0 + a1;
      }
    }
#pragma unroll
    for (int j = 0; j < 16; ++j) {
      int o = w * 16 + j;
      float v = (acc[j] - mean[o]) * rsqrtf(var[o] + BN_EPS) * gamma[o] + beta[o];
      sv[o * 64 + si] = v > 0.f ? v : 0.f;
    }
  }
  __syncthreads();

  float kreg[27];
#pragma unroll
  for (int j = 0; j < KK; ++j) kreg[j] = 0.f;
#pragma unroll
  for (int e = 0; e < 8; ++e) {
    float xv[8];
#pragma unroll
    for (int c = 0; c < 8; ++c) xv[c] = sv[(e * 8 + c) * 64 + si];
    const float* wsw = wsp + (g * KK) * CC + e * 8;
#pragma unroll
    for (int j = 0; j < KK; ++j) {
      const float* r = wsw + j * CC;
      float a0 = 0.f, a1 = 0.f;
#pragma unroll
      for (int c = 0; c < 8; c += 2) {
        a0 = fmaf(r[c],     xv[c],     a0);
        a1 = fmaf(r[c + 1], xv[c + 1], a1);
      }
      kreg[j] += a0 + a1;
    }
  }

  {
    const int c0 = g << 3;
    const float* xc0 = xb + ((size_t)c0 << 15);
    float oacc[8];
#pragma unroll
    for (int i = 0; i < 8; ++i) oacc[i] = 0.f;
#pragma unroll
    for (int k = 0; k < KK; ++k) {
      int off = offs[(k << 6) + si];
      float kv = kreg[k];
      if (off >= 0) {
#pragma unroll
        for (int c8 = 0; c8 < 8; ++c8)
          oacc[c8] = fmaf(kv, xc0[off + (c8 << 15)], oacc[c8]);
      }
    }
    float* ob = out + (((size_t)b * CC + c0) << 15) + s0 + si;
#pragma unroll
    for (int i = 0; i < 8; ++i) ob[(size_t)i << 15] = oacc[i];
  }
}

extern "C" void kernel_launch(void* const* d_in, const int* in_sizes, int n_in,
                              void* d_out, int out_size, void* d_ws, size_t ws_size,
                              hipStream_t stream) {
  const float* x     = (const float*)d_in[0];
  const float* wr    = (const float*)d_in[1];
  const float* wsp   = (const float*)d_in[2];
  const float* gamma = (const float*)d_in[3];
  const float* beta  = (const float*)d_in[4];
  const float* mean  = (const float*)d_in[5];
  const float* var   = (const float*)d_in[6];
  float* out = (float*)d_out;

  const size_t need = XT_FLOATS * sizeof(float);  // 16.8 MB
  if (ws_size >= need) {
    float* xT = (float*)d_ws;
    xpose_kernel<<<BB * (S_TOT / 64), 256, 0, stream>>>(x, xT);
    invol_fused_xt<<<BB * 2 * (S_TOT / 64), 256, 0, stream>>>(
        xT, wr, wsp, gamma, beta, mean, var, out);
  } else {
    invol_fused<<<BB * 2 * (S_TOT / 64), 256, 0, stream>>>(
        x, wr, wsp, gamma, beta, mean, var, out);
  }
}